// Round 6
// baseline (581.721 us; speedup 1.0000x reference)
//
#include <hip/hip_runtime.h>
#include <stdint.h>
#include <string.h>
#include <math.h>

// ---------------------------------------------------------------------------
// FlashThermodynamicAttention — exact replication of the JAX reference.
// Bit-exact recipe (verified R0-R4, absmax = 0): partitionable threefry
// (counter (0, m), bits = y0 ^ y1), XLA:CPU Cephes expf (non-fused),
// betas via double-rounded log/exp (jit const-folding).
//
// R5: I$-resident rolled loop (~2.7 KB body):
//   - t/hf/lr loops rolled (#pragma unroll 1); only the 4-site jj block
//     unrolled. Uniform code for every site.
//   - threshold via LDS broadcast read: idx = 2*cnt + e; e is wave-uniform
//     SALU; cnt bits via v_bfe on SWAR planes. <=9 distinct words in 9
//     distinct banks -> conflict-free broadcast, LDS pipe parallel to VALU.
//   - keys per half-sweep via scalar kernarg loads (runtime index, SALU).
//   - keeps R4 lane-pair split (8 waves/SIMD), 32-bit board ops.
// ---------------------------------------------------------------------------

struct FtaParams {
  uint32_t hk[32][2];   // threefry key for each of 16 steps x 2 half-sweeps
  uint32_t K9[2][9];    // (cutoff << 9): update to +1 iff bits < K9[beta][h+4]
};

// Host-side threefry-2x32 (key derivation only).
static inline void tf2x32_host(uint32_t k0, uint32_t k1, uint32_t c0, uint32_t c1,
                               uint32_t& o0, uint32_t& o1) {
  uint32_t ks2 = k0 ^ k1 ^ 0x1BD11BDAu;
  uint32_t x0 = c0 + k0, x1 = c1 + k1;
#define TFR(r) { x0 += x1; x1 = (x1 << (r)) | (x1 >> (32 - (r))); x1 ^= x0; }
  TFR(13) TFR(15) TFR(26) TFR(6)
  x0 += k1;  x1 += ks2 + 1u;
  TFR(17) TFR(29) TFR(16) TFR(24)
  x0 += ks2; x1 += k0 + 2u;
  TFR(13) TFR(15) TFR(26) TFR(6)
  x0 += k0;  x1 += k1 + 3u;
  TFR(17) TFR(29) TFR(16) TFR(24)
  x0 += k1;  x1 += ks2 + 4u;
  TFR(13) TFR(15) TFR(26) TFR(6)
  x0 += ks2; x1 += k0 + 5u;
#undef TFR
  o0 = x0; o1 = x1;
}

// Device threefry-2x32, specialized for counter (0, m), 4 independent chains.
// m-args are pre-added x1 inits (m + K1). Returns y0 ^ y1 per chain.
__device__ __forceinline__ static void tf_bits4(
    uint32_t K0, uint32_t K1, uint32_t ks2,
    uint32_t i1, uint32_t i2, uint32_t i3, uint32_t i4, uint32_t i5,
    uint32_t m0, uint32_t m1, uint32_t m2, uint32_t m3,
    uint32_t& o0, uint32_t& o1, uint32_t& o2, uint32_t& o3) {
#define ROTL(x, r) __builtin_amdgcn_alignbit((x), (x), 32u - (r))
#define QR4(r)                                                             \
  a0 += a1; b0 += b1; c0 += c1; d0 += d1;                                  \
  a1 = ROTL(a1, r) ^ a0; b1 = ROTL(b1, r) ^ b0;                            \
  c1 = ROTL(c1, r) ^ c0; d1 = ROTL(d1, r) ^ d0;
#define INJ4(sx, si)                                                       \
  a0 += sx; b0 += sx; c0 += sx; d0 += sx;                                  \
  a1 += si; b1 += si; c1 += si; d1 += si;
  uint32_t a1 = m0, b1 = m1, c1 = m2, d1 = m3;
  uint32_t a0 = K0 + a1, b0 = K0 + b1, c0 = K0 + c1, d0 = K0 + d1;
  a1 = ROTL(a1, 13) ^ a0; b1 = ROTL(b1, 13) ^ b0;
  c1 = ROTL(c1, 13) ^ c0; d1 = ROTL(d1, 13) ^ d0;
  QR4(15) QR4(26) QR4(6)
  INJ4(K1, i1)
  QR4(17) QR4(29) QR4(16) QR4(24)
  INJ4(ks2, i2)
  QR4(13) QR4(15) QR4(26) QR4(6)
  INJ4(K0, i3)
  QR4(17) QR4(29) QR4(16) QR4(24)
  INJ4(K1, i4)
  QR4(13) QR4(15) QR4(26) QR4(6)
  a0 += ks2; b0 += ks2; c0 += ks2; d0 += ks2;
  a1 += i5;  b1 += i5;  c1 += i5;  d1 += i5;
  o0 = a0 ^ a1; o1 = b0 ^ b1; o2 = c0 ^ c1; o3 = d0 ^ d1;
#undef QR4
#undef INJ4
#undef ROTL
}

// ---------------------------------------------------------------------------
// Device kernel: one LANE PAIR per 8x8 grid; each lane holds a 4x8 half in a
// 32-bit board. Odd lane's half is stored 180-degree rotated.
// ---------------------------------------------------------------------------
__global__ __launch_bounds__(256, 8) void fta_kernel(const float* __restrict__ v,
                                                     float* __restrict__ out,
                                                     FtaParams P) {
  __shared__ uint32_t sK[18];   // thresholds [beta][idx]
  if (threadIdx.x == 0) {
#pragma unroll
    for (int q = 0; q < 18; ++q) sK[q] = P.K9[q / 9][q % 9];
  }
  __syncthreads();

  uint32_t tid = blockIdx.x * 256u + threadIdx.x;
  const int half = (int)(tid & 1u);       // 0: rows 0-3; 1: rows 4-7 rotated
  uint32_t g = tid >> 1;                  // grid id = ((b*16+h)*4096+n)
  uint32_t b = g >> 16;
  uint32_t h = (g >> 12) & 15u;
  uint32_t n = g & 4095u;

  // float base for this lane's 32 values
  size_t voff = ((size_t)(b * 4096u + n)) * 1024u + (size_t)h * 64u
              + (size_t)(half * 32);

  // natural packing: bit idx = (v[voff+idx] > 0)
  uint32_t nat = 0u;
#pragma unroll
  for (int k = 0; k < 32; k += 4) {
    float4 a = *reinterpret_cast<const float4*>(v + voff + k);
    nat |= ((uint32_t)(a.x > 0.0f)) << (k + 0);
    nat |= ((uint32_t)(a.y > 0.0f)) << (k + 1);
    nat |= ((uint32_t)(a.z > 0.0f)) << (k + 2);
    nat |= ((uint32_t)(a.w > 0.0f)) << (k + 3);
  }
  // local board: odd half is bit-reversed (local L <-> global 63-L)
  uint32_t bd = half ? __brev(nat) : nat;

  const uint32_t mpc = g * 64u + (half ? 63u : 0u);  // counter base
  const int sgn = half ? -1 : 1;                     // counter step per local L

#pragma unroll 1
  for (int t = 0; t < 16; ++t) {
    const uint32_t koff = (t < 8) ? 0u : 9u;   // threshold set (beta)
#pragma unroll 1
    for (int hf = 0; hf < 2; ++hf) {
      const uint32_t K0 = P.hk[2 * t + hf][0];
      const uint32_t K1 = P.hk[2 * t + hf][1];
      const uint32_t ks2 = K0 ^ K1 ^ 0x1BD11BDAu;
      const uint32_t i1 = ks2 + 1u, i2 = K0 + 2u, i3 = K1 + 3u,
                     i4 = ks2 + 4u, i5 = K0 + 5u;
      const uint32_t cKp = mpc + K1;   // per-site x1 = cKp + sgn*L
      // checkerboard in local coords (same for both halves):
      const uint32_t pm = hf ? 0xAA55AA55u : 0x55AA55AAu;

      // ---- seam exchange: partner's local row 3, column-reversed ----
      uint32_t myrow3 = bd >> 24;
      uint32_t xrow = (uint32_t)__shfl_xor((int)myrow3, 1, 64);
      uint32_t xb = __brev(xrow) >> 24;   // rev8: bit lc = partner global col lc

      // ---- bit-sliced neighbor counts (32-bit, all 32 local sites) ----
      uint32_t U  = (bd >> 8) | (xb << 24);        // local row+1 (seam at row 3)
      uint32_t D  = bd << 8;                       // local row-1 (0 at row 0)
      uint32_t Lp = (bd >> 1) & 0x7f7f7f7fu;       // local col+1
      uint32_t Rp = (bd << 1) & 0xfefefefeu;       // local col-1
      uint32_t t0 = U ^ D,  ca = U & D;
      uint32_t t1 = Lp ^ Rp, cb = Lp & Rp;
      uint32_t c0 = t0 ^ t1, cc = t0 & t1;
      uint32_t cx = ca ^ cb;
      uint32_t c1 = cx ^ cc;
      uint32_t c2 = (ca & cb) | (cc & cx);

      uint32_t acc = 0u;
#pragma unroll 1
      for (int lr = 0; lr < 4; ++lr) {
        const uint32_t j0 = (uint32_t)((lr + 1 + hf) & 1);  // wave-uniform
        const uint32_t L0 = (uint32_t)lr * 8u + j0;
        const uint32_t e0 = (lr == 0) ? 1u : 0u;            // missing row below

        // per-jj wave-uniform threshold-table byte bases: 4*(koff + e)
        // lc = j0 + 2*jj; e = e0 + (lc==0) + (lc==7)
        uint32_t sb0 = 4u * (koff + e0 + (j0 == 0u ? 1u : 0u));   // jj=0
        uint32_t sb1 = 4u * (koff + e0);                          // jj=1
        uint32_t sb2 = 4u * (koff + e0);                          // jj=2
        uint32_t sb3 = 4u * (koff + e0 + (j0 == 1u ? 1u : 0u));   // jj=3

        // ---- per-site threshold fetch (LDS broadcast, conflict-free) ----
        const char* sKb = (const char*)sK;
        uint32_t thr[4];
#pragma unroll
        for (int jj = 0; jj < 4; ++jj) {
          uint32_t Lv = L0 + 2u * (uint32_t)jj;
          uint32_t x = (c0 >> Lv) & 1u;
          uint32_t y = (c1 >> Lv) & 1u;
          uint32_t z = (c2 >> Lv) & 1u;
          uint32_t sb = (jj == 0) ? sb0 : (jj == 1) ? sb1 : (jj == 2) ? sb2 : sb3;
          uint32_t baddr = sb + 8u * x + 16u * y + 32u * z;  // 4*(s + 2*cnt)
          thr[jj] = *(const uint32_t*)(sKb + baddr);
        }

        // ---- 4 ciphers, interleaved chains ----
        uint32_t bits[4];
        tf_bits4(K0, K1, ks2, i1, i2, i3, i4, i5,
                 (uint32_t)((int)cKp + sgn * (int)(L0 + 0u)),
                 (uint32_t)((int)cKp + sgn * (int)(L0 + 2u)),
                 (uint32_t)((int)cKp + sgn * (int)(L0 + 4u)),
                 (uint32_t)((int)cKp + sgn * (int)(L0 + 6u)),
                 bits[0], bits[1], bits[2], bits[3]);

        // ---- accept ----
#pragma unroll
        for (int jj = 0; jj < 4; ++jj) {
          uint32_t Lv = L0 + 2u * (uint32_t)jj;
          acc |= ((bits[jj] < thr[jj]) ? 1u : 0u) << Lv;
        }
      }
      bd = (bd & ~pm) | acc;
    }
  }

  uint32_t nato = half ? __brev(bd) : bd;
#pragma unroll
  for (int k = 0; k < 32; k += 4) {
    float4 o;
    o.x = ((nato >> (k + 0)) & 1u) ? 1.0f : -1.0f;
    o.y = ((nato >> (k + 1)) & 1u) ? 1.0f : -1.0f;
    o.z = ((nato >> (k + 2)) & 1u) ? 1.0f : -1.0f;
    o.w = ((nato >> (k + 3)) & 1u) ? 1.0f : -1.0f;
    *reinterpret_cast<float4*>(out + voff + k) = o;
  }
}

// ---------------------------------------------------------------------------
// XLA:CPU vectorized expf (Cephes/Eigen pexp<float>), non-fused mul/add.
static float xla_expf(float xin) {
  const float exp_hi = 88.3762626647950f;
  const float exp_lo = -88.3762626647949f;
  const float LOG2EF = 1.44269504088896341f;
  const float C1 = 0.693359375f;
  const float C2 = -2.12194440e-4f;
  const float Pc0 = 1.9875691500E-4f;
  const float Pc1 = 1.3981999507E-3f;
  const float Pc2 = 8.3334519073E-3f;
  const float Pc3 = 4.1665795894E-2f;
  const float Pc4 = 1.6666665459E-1f;
  const float Pc5 = 5.0000001201E-1f;
#define MA(a, b, c) ((a) * (b) + (c))
  float x = xin;
  if (x > exp_hi) x = exp_hi;
  if (x < exp_lo) x = exp_lo;
  float fx = floorf(MA(x, LOG2EF, 0.5f));
  float tmp = C1 * fx;
  float z = C2 * fx;
  x = x - tmp;
  x = x - z;
  z = x * x;
  float y = MA(x, Pc0, Pc1);
  y = MA(y, x, Pc2);
  y = MA(y, x, Pc3);
  y = MA(y, x, Pc4);
  y = MA(y, x, Pc5);
  y = MA(y, z, x);
  y = y + 1.0f;
  int nn = (int)fx;
  uint32_t eb = (uint32_t)(nn + 127) << 23;
  float p2n;
  memcpy(&p2n, &eb, 4);
  float r = y * p2n;
  return r > xin ? r : xin;
#undef MA
}

extern "C" void kernel_launch(void* const* d_in, const int* in_sizes, int n_in,
                              void* d_out, int out_size, void* d_ws, size_t ws_size,
                              hipStream_t stream) {
  (void)in_sizes; (void)n_in; (void)d_ws; (void)ws_size; (void)out_size;
  const float* v = (const float*)d_in[2];  // inputs: q, k, v — only v used
  float* out = (float*)d_out;

  FtaParams P;

  // ---- key derivation (host, exact integer math) ----
  const uint32_t rk0 = 0u, rk1 = 1234u;  // jax.random.key(1234) -> (0, 1234)
  uint32_t kt[16][2];
  // partitionable fold-like split: child j = cipher(key, (0, j)) -> (y0, y1)
  for (uint32_t t = 0; t < 16; ++t) tf2x32_host(rk0, rk1, 0u, t, kt[t][0], kt[t][1]);
  for (int t = 0; t < 16; ++t) {
    uint32_t a0, a1, b0, b1;
    tf2x32_host(kt[t][0], kt[t][1], 0u, 0u, a0, a1);  // k0 (first half-sweep)
    tf2x32_host(kt[t][0], kt[t][1], 0u, 1u, b0, b1);  // k1 (second half-sweep)
    P.hk[2 * t + 0][0] = a0; P.hk[2 * t + 0][1] = a1;
    P.hk[2 * t + 1][0] = b0; P.hk[2 * t + 1][1] = b1;
  }

  // ---- betas: jit const-folding path (HloEvaluator -> double-rounded) ----
  float bet[2];
  bet[0] = (float)exp((double)(float)log((double)0.8f));
  bet[1] = (float)exp((double)(float)log((double)1.2f));

  // ---- sigmoid cutoffs: u < p  <=>  bits < (ceil(p * 2^23) << 9) ----
  for (int s = 0; s < 2; ++s) {
    float x2b = 2.0f * bet[s];
    for (int hh = -4; hh <= 4; ++hh) {
      float xh = x2b * (float)hh;       // fl(2*beta*h), as in JAX
      float e = xla_expf(-xh);          // exp(-x)
      float p = 1.0f / (1.0f + e);      // LogisticExpander form
      double pd = (double)p * 8388608.0;  // exact in double
      uint64_t kc = (uint64_t)ceil(pd);
      uint64_t k9 = kc << 9;
      P.K9[s][hh + 4] = (k9 > 0xFFFFFFFFull) ? 0xFFFFFFFFu : (uint32_t)k9;
    }
  }

  fta_kernel<<<dim3(2048), dim3(256), 0, stream>>>(v, out, P);
}

// Round 7
// 520.127 us; speedup vs baseline: 1.1184x; 1.1184x over previous
//
#include <hip/hip_runtime.h>
#include <stdint.h>
#include <string.h>
#include <math.h>

// ---------------------------------------------------------------------------
// FlashThermodynamicAttention — exact replication of the JAX reference.
// Bit-exact recipe (verified R0-R5, absmax = 0): partitionable threefry
// (counter (0, m), bits = y0 ^ y1), XLA:CPU Cephes expf (non-fused),
// betas via double-rounded log/exp (jit const-folding).
//
// R6 = R4 structure (unrolled, lane-pair split, 8 waves/SIMD) +
//   - thresholds pinned to VGPRs (legal 1-instr v_cndmask selects; SGPR
//     table forced a v_mov per select due to the 1-SGPR-read rule)
//   - seam exchange via DPP quad_perm (lane^1) instead of ds_bpermute
// ---------------------------------------------------------------------------

struct FtaParams {
  uint32_t hk[32][2];   // threefry key for each of 16 steps x 2 half-sweeps
  uint32_t K9[2][9];    // (cutoff << 9): update to +1 iff bits < K9[beta][h+4]
};

// Host-side threefry-2x32 (key derivation only).
static inline void tf2x32_host(uint32_t k0, uint32_t k1, uint32_t c0, uint32_t c1,
                               uint32_t& o0, uint32_t& o1) {
  uint32_t ks2 = k0 ^ k1 ^ 0x1BD11BDAu;
  uint32_t x0 = c0 + k0, x1 = c1 + k1;
#define TFR(r) { x0 += x1; x1 = (x1 << (r)) | (x1 >> (32 - (r))); x1 ^= x0; }
  TFR(13) TFR(15) TFR(26) TFR(6)
  x0 += k1;  x1 += ks2 + 1u;
  TFR(17) TFR(29) TFR(16) TFR(24)
  x0 += ks2; x1 += k0 + 2u;
  TFR(13) TFR(15) TFR(26) TFR(6)
  x0 += k0;  x1 += k1 + 3u;
  TFR(17) TFR(29) TFR(16) TFR(24)
  x0 += k1;  x1 += ks2 + 4u;
  TFR(13) TFR(15) TFR(26) TFR(6)
  x0 += ks2; x1 += k0 + 5u;
#undef TFR
  o0 = x0; o1 = x1;
}

// Device threefry-2x32, specialized for counter (0, m), 4 independent chains.
// m-args are pre-added x1 inits (m + K1). Returns y0 ^ y1 per chain.
__device__ __forceinline__ static void tf_bits4(
    uint32_t K0, uint32_t K1, uint32_t ks2,
    uint32_t i1, uint32_t i2, uint32_t i3, uint32_t i4, uint32_t i5,
    uint32_t m0, uint32_t m1, uint32_t m2, uint32_t m3,
    uint32_t& o0, uint32_t& o1, uint32_t& o2, uint32_t& o3) {
#define ROTL(x, r) __builtin_amdgcn_alignbit((x), (x), 32u - (r))
#define QR4(r)                                                             \
  a0 += a1; b0 += b1; c0 += c1; d0 += d1;                                  \
  a1 = ROTL(a1, r) ^ a0; b1 = ROTL(b1, r) ^ b0;                            \
  c1 = ROTL(c1, r) ^ c0; d1 = ROTL(d1, r) ^ d0;
#define INJ4(sx, si)                                                       \
  a0 += sx; b0 += sx; c0 += sx; d0 += sx;                                  \
  a1 += si; b1 += si; c1 += si; d1 += si;
  uint32_t a1 = m0, b1 = m1, c1 = m2, d1 = m3;
  uint32_t a0 = K0 + a1, b0 = K0 + b1, c0 = K0 + c1, d0 = K0 + d1;
  a1 = ROTL(a1, 13) ^ a0; b1 = ROTL(b1, 13) ^ b0;
  c1 = ROTL(c1, 13) ^ c0; d1 = ROTL(d1, 13) ^ d0;
  QR4(15) QR4(26) QR4(6)
  INJ4(K1, i1)
  QR4(17) QR4(29) QR4(16) QR4(24)
  INJ4(ks2, i2)
  QR4(13) QR4(15) QR4(26) QR4(6)
  INJ4(K0, i3)
  QR4(17) QR4(29) QR4(16) QR4(24)
  INJ4(K1, i4)
  QR4(13) QR4(15) QR4(26) QR4(6)
  a0 += ks2; b0 += ks2; c0 += ks2; d0 += ks2;
  a1 += i5;  b1 += i5;  c1 += i5;  d1 += i5;
  o0 = a0 ^ a1; o1 = b0 ^ b1; o2 = c0 ^ c1; o3 = d0 ^ d1;
#undef QR4
#undef INJ4
#undef ROTL
}

// ---------------------------------------------------------------------------
// Device kernel: one LANE PAIR per 8x8 grid; each lane holds a 4x8 half in a
// 32-bit board. Odd lane's half is stored 180-degree rotated.
// ---------------------------------------------------------------------------
__global__ __launch_bounds__(256, 8) void fta_kernel(const float* __restrict__ v,
                                                     float* __restrict__ out,
                                                     FtaParams P) {
  uint32_t tid = blockIdx.x * 256u + threadIdx.x;
  const int half = (int)(tid & 1u);       // 0: rows 0-3; 1: rows 4-7 rotated
  uint32_t g = tid >> 1;                  // grid id = ((b*16+h)*4096+n)
  uint32_t b = g >> 16;
  uint32_t h = (g >> 12) & 15u;
  uint32_t n = g & 4095u;

  // float base for this lane's 32 values
  size_t voff = ((size_t)(b * 4096u + n)) * 1024u + (size_t)h * 64u
              + (size_t)(half * 32);

  // natural packing: bit idx = (v[voff+idx] > 0)
  uint32_t nat = 0u;
#pragma unroll
  for (int k = 0; k < 32; k += 4) {
    float4 a = *reinterpret_cast<const float4*>(v + voff + k);
    nat |= ((uint32_t)(a.x > 0.0f)) << (k + 0);
    nat |= ((uint32_t)(a.y > 0.0f)) << (k + 1);
    nat |= ((uint32_t)(a.z > 0.0f)) << (k + 2);
    nat |= ((uint32_t)(a.w > 0.0f)) << (k + 3);
  }
  // local board: odd half is bit-reversed (local L <-> global 63-L)
  uint32_t bd = half ? __brev(nat) : nat;

  const uint32_t mpc = g * 64u + (half ? 63u : 0u);  // counter base
  const int sgn = half ? -1 : 1;                     // counter step per local L

  // Threshold set for the current beta, PINNED to VGPRs so every tree select
  // is a single legal v_cndmask (two VGPR sources).
  uint32_t K[9];
#pragma unroll
  for (int q = 0; q < 9; ++q) {
    uint32_t x = P.K9[0][q];
    asm("" : "+v"(x));
    K[q] = x;
  }

  // Checkerboard masks in local coords (same for both halves):
  const uint32_t PM[2] = { 0x55AA55AAu, 0xAA55AA55u };

  for (int t = 0; t < 16; ++t) {
    if (t == 8) {
#pragma unroll
      for (int q = 0; q < 9; ++q) {
        uint32_t x = P.K9[1][q];
        asm("" : "+v"(x));
        K[q] = x;
      }
    }
#pragma unroll
    for (int hf = 0; hf < 2; ++hf) {
      const uint32_t K0 = P.hk[2 * t + hf][0];
      const uint32_t K1 = P.hk[2 * t + hf][1];
      const uint32_t ks2 = K0 ^ K1 ^ 0x1BD11BDAu;
      const uint32_t i1 = ks2 + 1u, i2 = K0 + 2u, i3 = K1 + 3u,
                     i4 = ks2 + 4u, i5 = K0 + 5u;
      const uint32_t cKp = mpc + K1;   // per-site x1 = cKp + sgn*L

      // ---- seam exchange via DPP: lane^1 (quad_perm [1,0,3,2]) ----
      uint32_t myrow3 = bd >> 24;
      uint32_t xrow = (uint32_t)__builtin_amdgcn_mov_dpp((int)myrow3,
                                                         0xB1, 0xF, 0xF, true);
      uint32_t xb = __brev(xrow) >> 24;   // rev8: bit lc = partner col lc

      // ---- bit-sliced neighbor counts (32-bit, all 32 local sites) ----
      uint32_t U  = (bd >> 8) | (xb << 24);        // local row+1 (seam row 3)
      uint32_t D  = bd << 8;                       // local row-1 (0 at row 0)
      uint32_t Lp = (bd >> 1) & 0x7f7f7f7fu;       // local col+1
      uint32_t Rp = (bd << 1) & 0xfefefefeu;       // local col-1
      uint32_t t0 = U ^ D,  ca = U & D;
      uint32_t t1 = Lp ^ Rp, cb = Lp & Rp;
      uint32_t c0 = t0 ^ t1, cc = t0 & t1;
      uint32_t cx = ca ^ cb;
      uint32_t c1 = cx ^ cc;
      uint32_t c2 = (ca & cb) | (cc & cx);

      uint32_t acc = 0u;
#pragma unroll
      for (int lr = 0; lr < 4; ++lr) {
        const int j0 = (lr + 1 + hf) & 1;
        const int L0 = lr * 8 + j0;
        uint32_t bits[4];
        tf_bits4(K0, K1, ks2, i1, i2, i3, i4, i5,
                 (uint32_t)((int)cKp + sgn * (L0 + 0)),
                 (uint32_t)((int)cKp + sgn * (L0 + 2)),
                 (uint32_t)((int)cKp + sgn * (L0 + 4)),
                 (uint32_t)((int)cKp + sgn * (L0 + 6)),
                 bits[0], bits[1], bits[2], bits[3]);
#pragma unroll
        for (int jj = 0; jj < 4; ++jj) {
          const int lc = j0 + 2 * jj;
          const int L = lr * 8 + lc;
          uint32_t b0v = c0 & (1u << L);
          uint32_t b1v = c1 & (1u << L);
          // boundary class in local coords (row 3 = seam-interior):
          const int e = (int)(lr == 0) + (int)(lc == 0) + (int)(lc == 7);
          uint32_t thr;
          if (e == 0) {            // interior: K[0,2,4,6,8] by cnt 0..4
            uint32_t b2v = c2 & (1u << L);
            uint32_t tA = b0v ? K[2] : K[0];
            uint32_t tB = b0v ? K[6] : K[4];
            uint32_t tC = b1v ? tB : tA;
            thr = b2v ? K[8] : tC;
          } else if (e == 1) {     // edge: K[1,3,5,7] by cnt 0..3
            uint32_t tA = b0v ? K[3] : K[1];
            uint32_t tB = b0v ? K[7] : K[5];
            thr = b1v ? tB : tA;
          } else {                 // corner: K[2,4,6] by cnt 0..2
            uint32_t tA = b0v ? K[4] : K[2];
            thr = b1v ? K[6] : tA;
          }
          uint32_t nb = (bits[jj] < thr) ? 1u : 0u;
          acc |= nb << L;
        }
      }
      bd = (bd & ~PM[hf]) | acc;
    }
  }

  uint32_t nato = half ? __brev(bd) : bd;
#pragma unroll
  for (int k = 0; k < 32; k += 4) {
    float4 o;
    o.x = ((nato >> (k + 0)) & 1u) ? 1.0f : -1.0f;
    o.y = ((nato >> (k + 1)) & 1u) ? 1.0f : -1.0f;
    o.z = ((nato >> (k + 2)) & 1u) ? 1.0f : -1.0f;
    o.w = ((nato >> (k + 3)) & 1u) ? 1.0f : -1.0f;
    *reinterpret_cast<float4*>(out + voff + k) = o;
  }
}

// ---------------------------------------------------------------------------
// XLA:CPU vectorized expf (Cephes/Eigen pexp<float>), non-fused mul/add.
static float xla_expf(float xin) {
  const float exp_hi = 88.3762626647950f;
  const float exp_lo = -88.3762626647949f;
  const float LOG2EF = 1.44269504088896341f;
  const float C1 = 0.693359375f;
  const float C2 = -2.12194440e-4f;
  const float Pc0 = 1.9875691500E-4f;
  const float Pc1 = 1.3981999507E-3f;
  const float Pc2 = 8.3334519073E-3f;
  const float Pc3 = 4.1665795894E-2f;
  const float Pc4 = 1.6666665459E-1f;
  const float Pc5 = 5.0000001201E-1f;
#define MA(a, b, c) ((a) * (b) + (c))
  float x = xin;
  if (x > exp_hi) x = exp_hi;
  if (x < exp_lo) x = exp_lo;
  float fx = floorf(MA(x, LOG2EF, 0.5f));
  float tmp = C1 * fx;
  float z = C2 * fx;
  x = x - tmp;
  x = x - z;
  z = x * x;
  float y = MA(x, Pc0, Pc1);
  y = MA(y, x, Pc2);
  y = MA(y, x, Pc3);
  y = MA(y, x, Pc4);
  y = MA(y, x, Pc5);
  y = MA(y, z, x);
  y = y + 1.0f;
  int nn = (int)fx;
  uint32_t eb = (uint32_t)(nn + 127) << 23;
  float p2n;
  memcpy(&p2n, &eb, 4);
  float r = y * p2n;
  return r > xin ? r : xin;
#undef MA
}

extern "C" void kernel_launch(void* const* d_in, const int* in_sizes, int n_in,
                              void* d_out, int out_size, void* d_ws, size_t ws_size,
                              hipStream_t stream) {
  (void)in_sizes; (void)n_in; (void)d_ws; (void)ws_size; (void)out_size;
  const float* v = (const float*)d_in[2];  // inputs: q, k, v — only v used
  float* out = (float*)d_out;

  FtaParams P;

  // ---- key derivation (host, exact integer math) ----
  const uint32_t rk0 = 0u, rk1 = 1234u;  // jax.random.key(1234) -> (0, 1234)
  uint32_t kt[16][2];
  // partitionable fold-like split: child j = cipher(key, (0, j)) -> (y0, y1)
  for (uint32_t t = 0; t < 16; ++t) tf2x32_host(rk0, rk1, 0u, t, kt[t][0], kt[t][1]);
  for (int t = 0; t < 16; ++t) {
    uint32_t a0, a1, b0, b1;
    tf2x32_host(kt[t][0], kt[t][1], 0u, 0u, a0, a1);  // k0 (first half-sweep)
    tf2x32_host(kt[t][0], kt[t][1], 0u, 1u, b0, b1);  // k1 (second half-sweep)
    P.hk[2 * t + 0][0] = a0; P.hk[2 * t + 0][1] = a1;
    P.hk[2 * t + 1][0] = b0; P.hk[2 * t + 1][1] = b1;
  }

  // ---- betas: jit const-folding path (HloEvaluator -> double-rounded) ----
  float bet[2];
  bet[0] = (float)exp((double)(float)log((double)0.8f));
  bet[1] = (float)exp((double)(float)log((double)1.2f));

  // ---- sigmoid cutoffs: u < p  <=>  bits < (ceil(p * 2^23) << 9) ----
  for (int s = 0; s < 2; ++s) {
    float x2b = 2.0f * bet[s];
    for (int hh = -4; hh <= 4; ++hh) {
      float xh = x2b * (float)hh;       // fl(2*beta*h), as in JAX
      float e = xla_expf(-xh);          // exp(-x)
      float p = 1.0f / (1.0f + e);      // LogisticExpander form
      double pd = (double)p * 8388608.0;  // exact in double
      uint64_t kc = (uint64_t)ceil(pd);
      uint64_t k9 = kc << 9;
      P.K9[s][hh + 4] = (k9 > 0xFFFFFFFFull) ? 0xFFFFFFFFu : (uint32_t)k9;
    }
  }

  fta_kernel<<<dim3(2048), dim3(256), 0, stream>>>(v, out, P);
}